// Round 1
// baseline (899.442 us; speedup 1.0000x reference)
//
#include <hip/hip_runtime.h>

#define DX 128
#define DY 128
#define DZ 128
#define NVERT (DX * DY * DZ)   // 2097152

// One thread per point: compute the 8 trilinear corner weights and
// atomicAdd them into the per-batch 128^3 grid.
// Coordinates guaranteed in [-0.98, 0.98] -> all 8 corners in-grid, no
// bounds checks (mirrors the reference's setup_inputs guarantee).
__global__ __launch_bounds__(256) void splat_kernel(
    const float* __restrict__ pts,   // (B, N, 3) flat
    float* __restrict__ out,         // (B, NVERT) flat
    int n_per_batch,                 // N
    int total)                       // B * N
{
    int t = blockIdx.x * blockDim.x + threadIdx.x;
    if (t >= total) return;

    float px = pts[3 * t + 0] * 64.0f;
    float py = pts[3 * t + 1] * 64.0f;
    float pz = pts[3 * t + 2] * 64.0f;

    float lx = floorf(px), ly = floorf(py), lz = floorf(pz);
    float fx = px - lx, fy = py - ly, fz = pz - lz;

    int ix = (int)lx + 64;
    int iy = (int)ly + 64;
    int iz = (int)lz + 64;

    int b = t / n_per_batch;
    float* o = out + (size_t)b * NVERT;

    size_t base = ((size_t)ix * DY + (size_t)iy) * DZ + (size_t)iz;

    float gx[2] = {1.0f - fx, fx};
    float gy[2] = {1.0f - fy, fy};
    float gz[2] = {1.0f - fz, fz};

#pragma unroll
    for (int dx = 0; dx < 2; ++dx) {
#pragma unroll
        for (int dy = 0; dy < 2; ++dy) {
#pragma unroll
            for (int dz = 0; dz < 2; ++dz) {
                float w = gx[dx] * gy[dy] * gz[dz];
                atomicAdd(o + base + (size_t)dx * (DY * DZ) + dy * DZ + dz, w);
            }
        }
    }
}

extern "C" void kernel_launch(void* const* d_in, const int* in_sizes, int n_in,
                              void* d_out, int out_size, void* d_ws, size_t ws_size,
                              hipStream_t stream) {
    const float* pred = (const float*)d_in[0];
    const float* gt   = (const float*)d_in[1];
    float* out = (float*)d_out;

    int total = in_sizes[0] / 3;               // B * N points per cloud
    int B = out_size / (2 * NVERT);            // out = [pred_grid | gt_grid], each B*NVERT
    int n_per_batch = total / B;               // N

    // d_out is poisoned to 0xAA before every timed launch -> zero it.
    hipMemsetAsync(d_out, 0, (size_t)out_size * sizeof(float), stream);

    int threads = 256;
    int blocks = (total + threads - 1) / threads;
    splat_kernel<<<blocks, threads, 0, stream>>>(pred, out, n_per_batch, total);
    splat_kernel<<<blocks, threads, 0, stream>>>(gt, out + (size_t)B * NVERT, n_per_batch, total);
}

// Round 2
// 679.774 us; speedup vs baseline: 1.3231x; 1.3231x over previous
//
#include <hip/hip_runtime.h>

#define DXYZ 128
#define NVERT (DXYZ * DXYZ * DXYZ)     // 2097152 voxels per (cloud,batch) grid
#define BIN 16                          // bin/region edge in voxels
#define NBIN_D (DXYZ / BIN)             // 8 bins per dim
#define BINS_PER_GRID (NBIN_D * NBIN_D * NBIN_D)  // 512

// ---------------- Pass 1: histogram points into spatial bins ----------------
__global__ __launch_bounds__(256) void hist_kernel(
    const float* __restrict__ p0, const float* __restrict__ p1,
    unsigned* __restrict__ counts,
    int total_per_cloud, int n_per_batch, int B)
{
    int t = blockIdx.x * blockDim.x + threadIdx.x;
    if (t >= 2 * total_per_cloud) return;
    int cloud = (t >= total_per_cloud) ? 1 : 0;
    int idx = t - cloud * total_per_cloud;
    const float* p = cloud ? p1 : p0;

    float px = p[3 * idx + 0] * 64.0f;
    float py = p[3 * idx + 1] * 64.0f;
    float pz = p[3 * idx + 2] * 64.0f;
    int ix = (int)floorf(px) + 64;
    int iy = (int)floorf(py) + 64;
    int iz = (int)floorf(pz) + 64;

    int b = idx / n_per_batch;
    int key = (cloud * B + b) * BINS_PER_GRID +
              ((ix >> 4) << 6) + ((iy >> 4) << 3) + (iz >> 4);
    atomicAdd(&counts[key], 1u);
}

// ---------------- Pass 2: exclusive scan of bin counts ----------------
__global__ __launch_bounds__(1024) void scan_kernel(
    const unsigned* __restrict__ counts,
    unsigned* __restrict__ bin_start,   // nkeys+1
    unsigned* __restrict__ cursor,      // nkeys
    int nkeys)
{
    __shared__ unsigned part[1024];
    int tid = threadIdx.x;
    int chunk = (nkeys + 1023) / 1024;
    int lo = tid * chunk;
    unsigned s = 0;
    for (int i = 0; i < chunk; ++i) {
        int k = lo + i;
        if (k < nkeys) s += counts[k];
    }
    part[tid] = s;
    __syncthreads();
    for (int off = 1; off < 1024; off <<= 1) {
        unsigned v = (tid >= off) ? part[tid - off] : 0u;
        __syncthreads();
        part[tid] += v;
        __syncthreads();
    }
    unsigned run = (tid == 0) ? 0u : part[tid - 1];
    for (int i = 0; i < chunk; ++i) {
        int k = lo + i;
        if (k < nkeys) {
            bin_start[k] = run;
            cursor[k] = run;
            run += counts[k];
        }
    }
    if (tid == 1023) bin_start[nkeys] = run;  // total points sentinel
}

// ---------------- Pass 3: scatter points into bin-sorted order ----------------
__global__ __launch_bounds__(256) void scatter_kernel(
    const float* __restrict__ p0, const float* __restrict__ p1,
    unsigned* __restrict__ cursor,
    float4* __restrict__ sorted,
    int total_per_cloud, int n_per_batch, int B)
{
    int t = blockIdx.x * blockDim.x + threadIdx.x;
    if (t >= 2 * total_per_cloud) return;
    int cloud = (t >= total_per_cloud) ? 1 : 0;
    int idx = t - cloud * total_per_cloud;
    const float* p = cloud ? p1 : p0;

    float px = p[3 * idx + 0] * 64.0f;
    float py = p[3 * idx + 1] * 64.0f;
    float pz = p[3 * idx + 2] * 64.0f;
    float lx = floorf(px), ly = floorf(py), lz = floorf(pz);
    int ix = (int)lx + 64;
    int iy = (int)ly + 64;
    int iz = (int)lz + 64;

    int b = idx / n_per_batch;
    int key = (cloud * B + b) * BINS_PER_GRID +
              ((ix >> 4) << 6) + ((iy >> 4) << 3) + (iz >> 4);
    unsigned slot = atomicAdd(&cursor[key], 1u);
    unsigned packed = (unsigned)ix | ((unsigned)iy << 8) | ((unsigned)iz << 16);
    sorted[slot] = make_float4(px - lx, py - ly, pz - lz, __uint_as_float(packed));
}

// ---------------- Pass 4: per-region gather + LDS accumulate + plain stores ----
__global__ __launch_bounds__(256) void gather_kernel(
    const float4* __restrict__ sorted,
    const unsigned* __restrict__ bin_start,
    float* __restrict__ out,
    int B)
{
    __shared__ float acc[BIN * BIN * BIN];  // 16 KB

    int bi = blockIdx.x;
    int r = bi & (BINS_PER_GRID - 1);
    int cb = bi >> 9;                 // cloud*B + batch
    int rx = r >> 6, ry = (r >> 3) & 7, rz = r & 7;
    int x0 = rx << 4, y0 = ry << 4, z0 = rz << 4;

    for (int i = threadIdx.x; i < BIN * BIN * BIN; i += blockDim.x) acc[i] = 0.0f;
    __syncthreads();

    int keybase = cb * BINS_PER_GRID;
    for (int sx = rx - 1; sx <= rx; ++sx) {
        if (sx < 0) continue;
        for (int sy = ry - 1; sy <= ry; ++sy) {
            if (sy < 0) continue;
            for (int sz = rz - 1; sz <= rz; ++sz) {
                if (sz < 0) continue;
                int k = keybase + (sx << 6) + (sy << 3) + sz;
                unsigned s = bin_start[k], e = bin_start[k + 1];
                for (unsigned i = s + threadIdx.x; i < e; i += blockDim.x) {
                    float4 pt = sorted[i];
                    unsigned pk = __float_as_uint(pt.w);
                    int lx = (int)(pk & 0xff) - x0;
                    int ly = (int)((pk >> 8) & 0xff) - y0;
                    int lz = (int)((pk >> 16) & 0xff) - z0;
                    float gx[2] = {1.0f - pt.x, pt.x};
                    float gy[2] = {1.0f - pt.y, pt.y};
                    float gz[2] = {1.0f - pt.z, pt.z};
#pragma unroll
                    for (int dx = 0; dx < 2; ++dx) {
                        int cx = lx + dx;
                        if ((unsigned)cx >= (unsigned)BIN) continue;
#pragma unroll
                        for (int dy = 0; dy < 2; ++dy) {
                            int cy = ly + dy;
                            if ((unsigned)cy >= (unsigned)BIN) continue;
#pragma unroll
                            for (int dz = 0; dz < 2; ++dz) {
                                int cz = lz + dz;
                                if ((unsigned)cz >= (unsigned)BIN) continue;
                                atomicAdd(&acc[(cx * BIN + cy) * BIN + cz],
                                          gx[dx] * gy[dy] * gz[dz]);
                            }
                        }
                    }
                }
            }
        }
    }
    __syncthreads();

    // Write the disjoint 16^3 region: 256 rows of 16 consecutive z-voxels.
    float* obase = out + (size_t)cb * NVERT;
    int row = threadIdx.x;               // (lx*16 + ly)
    int lx = row >> 4, ly = row & 15;
    size_t o = (((size_t)(x0 + lx) * DXYZ) + (size_t)(y0 + ly)) * DXYZ + z0;
    float4* op = (float4*)(obase + o);
    const float4* ap = (const float4*)&acc[row * BIN];
    op[0] = ap[0];
    op[1] = ap[1];
    op[2] = ap[2];
    op[3] = ap[3];
}

// ---------------- Fallback: round-1 direct atomic splat ----------------
__global__ __launch_bounds__(256) void splat_kernel(
    const float* __restrict__ pts, float* __restrict__ out,
    int n_per_batch, int total)
{
    int t = blockIdx.x * blockDim.x + threadIdx.x;
    if (t >= total) return;
    float px = pts[3 * t + 0] * 64.0f;
    float py = pts[3 * t + 1] * 64.0f;
    float pz = pts[3 * t + 2] * 64.0f;
    float lx = floorf(px), ly = floorf(py), lz = floorf(pz);
    float fx = px - lx, fy = py - ly, fz = pz - lz;
    int ix = (int)lx + 64, iy = (int)ly + 64, iz = (int)lz + 64;
    int b = t / n_per_batch;
    float* o = out + (size_t)b * NVERT;
    size_t base = ((size_t)ix * DXYZ + (size_t)iy) * DXYZ + (size_t)iz;
    float gx[2] = {1.0f - fx, fx}, gy[2] = {1.0f - fy, fy}, gz[2] = {1.0f - fz, fz};
#pragma unroll
    for (int dx = 0; dx < 2; ++dx)
#pragma unroll
        for (int dy = 0; dy < 2; ++dy)
#pragma unroll
            for (int dz = 0; dz < 2; ++dz)
                atomicAdd(o + base + (size_t)dx * (DXYZ * DXYZ) + dy * DXYZ + dz,
                          gx[dx] * gy[dy] * gz[dz]);
}

extern "C" void kernel_launch(void* const* d_in, const int* in_sizes, int n_in,
                              void* d_out, int out_size, void* d_ws, size_t ws_size,
                              hipStream_t stream) {
    const float* pred = (const float*)d_in[0];
    const float* gt   = (const float*)d_in[1];
    float* out = (float*)d_out;

    int total = in_sizes[0] / 3;           // B*N points per cloud
    int B = out_size / (2 * NVERT);
    int n_per_batch = total / B;
    int nkeys = 2 * B * BINS_PER_GRID;     // 4096 for B=4

    // Workspace layout
    size_t off_counts = 0;                          // nkeys u32
    size_t off_start  = 64 * 1024;                  // nkeys+1 u32
    size_t off_cursor = 128 * 1024;                 // nkeys u32
    size_t off_sorted = 256 * 1024;                 // 2*total float4
    size_t needed = off_sorted + (size_t)2 * total * sizeof(float4);

    if (ws_size < needed) {
        // Fallback: direct atomic splat (round-1 path)
        hipMemsetAsync(d_out, 0, (size_t)out_size * sizeof(float), stream);
        int blocks = (total + 255) / 256;
        splat_kernel<<<blocks, 256, 0, stream>>>(pred, out, n_per_batch, total);
        splat_kernel<<<blocks, 256, 0, stream>>>(gt, out + (size_t)B * NVERT,
                                                 n_per_batch, total);
        return;
    }

    char* ws = (char*)d_ws;
    unsigned* counts   = (unsigned*)(ws + off_counts);
    unsigned* binstart = (unsigned*)(ws + off_start);
    unsigned* cursor   = (unsigned*)(ws + off_cursor);
    float4*   sorted   = (float4*)(ws + off_sorted);

    hipMemsetAsync(counts, 0, (size_t)nkeys * sizeof(unsigned), stream);

    int pt_blocks = (2 * total + 255) / 256;
    hist_kernel<<<pt_blocks, 256, 0, stream>>>(pred, gt, counts,
                                               total, n_per_batch, B);
    scan_kernel<<<1, 1024, 0, stream>>>(counts, binstart, cursor, nkeys);
    scatter_kernel<<<pt_blocks, 256, 0, stream>>>(pred, gt, cursor, sorted,
                                                  total, n_per_batch, B);
    gather_kernel<<<2 * B * BINS_PER_GRID, 256, 0, stream>>>(sorted, binstart,
                                                             out, B);
}